// Round 2
// baseline (1922.856 us; speedup 1.0000x reference)
//
#include <hip/hip_runtime.h>
#include <hip/hip_bf16.h>
#include <math.h>

#define Bv 2
#define Tv 2048
#define Cv 1024
#define Hv 16
#define DHv 64
#define BTv (Bv*Tv)

// ---------------- fuse mix into weights ----------------
// out[h*DH+d, c] = sum_m mix[h,m] * w[m*DH+d, c]
__global__ __launch_bounds__(256) void fuse_w_kernel(
    const float* __restrict__ wq, const float* __restrict__ wk, const float* __restrict__ wv,
    const float* __restrict__ mq, const float* __restrict__ mk, const float* __restrict__ mv,
    float* __restrict__ oq, float* __restrict__ ok, float* __restrict__ ov)
{
    int row = blockIdx.x;           // 0 .. 3*C-1
    int sel = row / Cv;
    int r   = row % Cv;
    int h = r / DHv, d = r % DHv;
    const float* w   = sel==0 ? wq : (sel==1 ? wk : wv);
    const float* mix = sel==0 ? mq : (sel==1 ? mk : mv);
    float* out       = sel==0 ? oq : (sel==1 ? ok : ov);
    float mrow[Hv];
#pragma unroll
    for (int m=0;m<Hv;++m) mrow[m] = mix[h*Hv + m];
    for (int c = threadIdx.x; c < Cv; c += 256) {
        float acc = 0.f;
#pragma unroll
        for (int m=0;m<Hv;++m) acc += mrow[m] * w[(m*DHv + d)*Cv + c];
        out[r*Cv + c] = acc;
    }
}

// ---------------- Y[M,N] = X[M,K] * W[N,K]^T (both K-contiguous) ----------------
#define GBM 64
#define GBN 64
#define GBK 16
#define GLD 68   // padded LDS stride (float4-aligned, 2-way banks only)

__global__ __launch_bounds__(256) void gemm_xwT_kernel(
    const float* __restrict__ X, const float* __restrict__ W, float* __restrict__ Y,
    int M, int N, int K)
{
    __shared__ float Xs[GBK][GLD];
    __shared__ float Ws[GBK][GLD];
    int bm = blockIdx.y * GBM;
    int bn = blockIdx.x * GBN;
    int tid = threadIdx.x;
    int tx = tid & 15, ty = tid >> 4;
    float acc[4][4] = {{0.f}};
    for (int k0 = 0; k0 < K; k0 += GBK) {
#pragma unroll
        for (int i=0;i<4;++i) {
            int idx = tid + i*256;       // 0..1023
            int r = idx >> 4, c = idx & 15;
            Xs[c][r] = X[(size_t)(bm + r)*K + k0 + c];
            Ws[c][r] = W[(size_t)(bn + r)*K + k0 + c];
        }
        __syncthreads();
#pragma unroll
        for (int kk=0; kk<GBK; ++kk) {
            float4 a4 = *(const float4*)&Xs[kk][ty*4];
            float4 b4 = *(const float4*)&Ws[kk][tx*4];
            float a[4] = {a4.x,a4.y,a4.z,a4.w};
            float b[4] = {b4.x,b4.y,b4.z,b4.w};
#pragma unroll
            for (int i=0;i<4;++i)
#pragma unroll
                for (int j=0;j<4;++j) acc[i][j] += a[i]*b[j];
        }
        __syncthreads();
    }
#pragma unroll
    for (int i=0;i<4;++i)
#pragma unroll
        for (int j=0;j<4;++j)
            Y[(size_t)(bm + ty*4 + i)*N + bn + tx*4 + j] = acc[i][j];
}

// ---------------- gates + RoPE + RMS-norm + k time-shift ----------------
// one wave per (b,t,h); lane = dim d
__global__ __launch_bounds__(256) void post_kernel(
    const float* __restrict__ x, const float* __restrict__ ve,
    const float* __restrict__ cosT, const float* __restrict__ sinT,
    const float* __restrict__ vegw, const float* __restrict__ atgw,
    float* __restrict__ q, const float* __restrict__ kraw,
    float* __restrict__ kshift, float* __restrict__ v, float* __restrict__ gateA)
{
    int bt = blockIdx.x;
    int t = bt & (Tv-1);
    int wave = threadIdx.x >> 6;
    int lane = threadIdx.x & 63;
    int h = blockIdx.y*4 + wave;
    int base = bt*Cv + h*DHv;

    // gates from x[..., :32] / x[..., :12]
    float gv  = (lane < 32) ? x[bt*Cv + lane] * vegw[h*32 + lane] : 0.f;
    float gaP = (lane < 12) ? x[bt*Cv + lane] * atgw[h*12 + lane] : 0.f;
#pragma unroll
    for (int off=32; off; off>>=1) {
        gv  += __shfl_xor(gv,  off);
        gaP += __shfl_xor(gaP, off);
    }
    float gateV = 2.f / (1.f + expf(-gv));
    float ga    = 1.f / (1.f + expf(-gaP));
    if (lane == 0) gateA[bt*Hv + h] = ga;

    // v += gate_v * ve
    v[base+lane] = v[base+lane] + gateV * ve[base+lane];

    float cs = cosT[t*32 + (lane & 31)];
    float sn = sinT[t*32 + (lane & 31)];

    // q: rope + rms (in place)
    float qa = q[base+lane];
    float qb = __shfl_xor(qa, 32);
    float qr = qa*cs + ((lane < 32) ? qb*sn : -qb*sn);
    float ss = qr*qr;
#pragma unroll
    for (int off=32; off; off>>=1) ss += __shfl_xor(ss, off);
    q[base+lane] = qr * rsqrtf(ss*(1.f/64.f) + 1e-6f);

    // k: rope + rms, then time-shift upper half into kshift
    float ka = kraw[base+lane];
    float kb = __shfl_xor(ka, 32);
    float kr = ka*cs + ((lane < 32) ? kb*sn : -kb*sn);
    float s2 = kr*kr;
#pragma unroll
    for (int off=32; off; off>>=1) s2 += __shfl_xor(s2, off);
    float kn = kr * rsqrtf(s2*(1.f/64.f) + 1e-6f);
    if (lane < 32) {
        kshift[base+lane] = kn;                 // lower half stays at t
    } else {
        if (t == 0)      kshift[base+lane] = kn;       // row 0 upper = own
        if (t+1 < Tv)    kshift[base + Cv + lane] = kn; // row t+1 upper = this t
    }
}

// ---------------- flash attention (f32), 4 q-rows per block ----------------
__global__ __launch_bounds__(256) void attn_kernel(
    const float* __restrict__ q, const float* __restrict__ kshift,
    const float* __restrict__ v, const float* __restrict__ gateA,
    float* __restrict__ y, const int* __restrict__ wptr)
{
    __shared__ float qs[4][DHv];
    __shared__ float ks[64][65];
    __shared__ float vs[64][65];
    __shared__ float ps[4][64];

    int qtile = blockIdx.x;       // 0..T/4-1
    int h = blockIdx.y;
    int b = blockIdx.z;
    int tid = threadIdx.x;
    int wave = tid >> 6, lane = tid & 63;
    int qi = qtile*4 + wave;
    int w = *wptr;
    bool use_w = !(w < 0 || w >= Tv-1);

    const size_t hoff = (size_t)h*DHv;
    qs[wave][lane] = q[((size_t)(b*Tv + qi))*Cv + hoff + lane];
    __syncthreads();

    float m = -INFINITY, l = 0.f, o = 0.f;
    const float scale = 0.125f;   // 1/sqrt(64)

    int ntiles = qtile/16 + 1;    // covers keys 0..qi
    for (int kt = 0; kt < ntiles; ++kt) {
        for (int i = tid; i < 64*64; i += 256) {
            int j = i >> 6, d = i & 63;
            size_t g = ((size_t)(b*Tv + kt*64 + j))*Cv + hoff + d;
            ks[j][d] = kshift[g];
            vs[j][d] = v[g];
        }
        __syncthreads();

        int kg = kt*64 + lane;
        float s = 0.f;
#pragma unroll
        for (int d=0; d<DHv; ++d) s += qs[wave][d] * ks[lane][d];
        bool valid = (kg <= qi) && (!use_w || (qi - kg <= w));
        s = valid ? s*scale : -INFINITY;

        float mt = s;
#pragma unroll
        for (int off=32; off; off>>=1) mt = fmaxf(mt, __shfl_xor(mt, off));
        float mnew = fmaxf(m, mt);
        float p = 0.f, alpha = 0.f, psum;
        if (mnew > -INFINITY) {
            alpha = expf(m - mnew);   // m=-inf -> 0
            p = expf(s - mnew);       // s=-inf -> 0
        }
        psum = p;
#pragma unroll
        for (int off=32; off; off>>=1) psum += __shfl_xor(psum, off);
        ps[wave][lane] = p;
        __syncthreads();
        if (mnew > -INFINITY) {
            float onew = o*alpha;
#pragma unroll
            for (int j=0;j<64;++j) onew += ps[wave][j]*vs[j][lane];
            o = onew;
            l = l*alpha + psum;
            m = mnew;
        }
        __syncthreads();
    }
    float ga = gateA[(size_t)(b*Tv + qi)*Hv + h];
    y[((size_t)(b*Tv + qi))*Cv + hoff + lane] = (o / l) * ga;
}

extern "C" void kernel_launch(void* const* d_in, const int* in_sizes, int n_in,
                              void* d_out, int out_size, void* d_ws, size_t ws_size,
                              hipStream_t stream) {
    const float* x    = (const float*)d_in[0];
    const float* ve   = (const float*)d_in[1];
    const float* cosT = (const float*)d_in[2];
    const float* sinT = (const float*)d_in[3];
    const float* cqw  = (const float*)d_in[4];
    const float* ckw  = (const float*)d_in[5];
    const float* cvw  = (const float*)d_in[6];
    const float* cpw  = (const float*)d_in[7];
    const float* vegw = (const float*)d_in[8];
    const float* atgw = (const float*)d_in[9];
    const float* qmix = (const float*)d_in[10];
    const float* kmix = (const float*)d_in[11];
    const float* vmix = (const float*)d_in[12];
    const int*   wsz  = (const int*)d_in[13];
    float* out = (float*)d_out;

    float* p  = (float*)d_ws;
    float* qw = p; p += Cv*Cv;
    float* kw = p; p += Cv*Cv;
    float* vw = p; p += Cv*Cv;
    float* q  = p; p += (size_t)BTv*Cv;
    float* kry= p; p += (size_t)BTv*Cv;   // k-raw, later reused as attention output y
    float* ksh= p; p += (size_t)BTv*Cv;   // k after rope/rms + time-shift
    float* v  = p; p += (size_t)BTv*Cv;
    float* ga = p; p += (size_t)BTv*Hv;

    fuse_w_kernel<<<3*Cv, 256, 0, stream>>>(cqw, ckw, cvw, qmix, kmix, vmix, qw, kw, vw);

    dim3 ggrid(Cv/GBN, BTv/GBM);
    gemm_xwT_kernel<<<ggrid, 256, 0, stream>>>(x, qw, q,   BTv, Cv, Cv);
    gemm_xwT_kernel<<<ggrid, 256, 0, stream>>>(x, kw, kry, BTv, Cv, Cv);
    gemm_xwT_kernel<<<ggrid, 256, 0, stream>>>(x, vw, v,   BTv, Cv, Cv);

    post_kernel<<<dim3(BTv, Hv/4), 256, 0, stream>>>(x, ve, cosT, sinT, vegw, atgw,
                                                     q, kry, ksh, v, ga);

    attn_kernel<<<dim3(Tv/4, Hv, Bv), 256, 0, stream>>>(q, ksh, v, ga, kry, wsz);

    gemm_xwT_kernel<<<ggrid, 256, 0, stream>>>(kry, cpw, out, BTv, Cv, Cv);
}

// Round 3
// 881.825 us; speedup vs baseline: 2.1805x; 2.1805x over previous
//
#include <hip/hip_runtime.h>
#include <hip/hip_bf16.h>
#include <math.h>

#define Bv 2
#define Tv 2048
#define Cv 1024
#define Hv 16
#define DHv 64
#define BTv (Bv*Tv)

typedef __attribute__((ext_vector_type(8))) short short8;
typedef __attribute__((ext_vector_type(4))) float f32x4;

__device__ __forceinline__ unsigned short f2bf(float f) {
    union { float f; unsigned u; } x; x.f = f;
    unsigned r = x.u + 0x7fffu + ((x.u >> 16) & 1u);
    return (unsigned short)(r >> 16);
}

// ---------------- fuse mix into weights ----------------
__global__ __launch_bounds__(256) void fuse_w_kernel(
    const float* __restrict__ wq, const float* __restrict__ wk, const float* __restrict__ wv,
    const float* __restrict__ mq, const float* __restrict__ mk, const float* __restrict__ mv,
    float* __restrict__ oq, float* __restrict__ ok, float* __restrict__ ov)
{
    int row = blockIdx.x;
    int sel = row / Cv;
    int r   = row % Cv;
    int h = r / DHv, d = r % DHv;
    const float* w   = sel==0 ? wq : (sel==1 ? wk : wv);
    const float* mix = sel==0 ? mq : (sel==1 ? mk : mv);
    float* out       = sel==0 ? oq : (sel==1 ? ok : ov);
    float mrow[Hv];
#pragma unroll
    for (int m=0;m<Hv;++m) mrow[m] = mix[h*Hv + m];
    for (int c = threadIdx.x; c < Cv; c += 256) {
        float acc = 0.f;
#pragma unroll
        for (int m=0;m<Hv;++m) acc += mrow[m] * w[(m*DHv + d)*Cv + c];
        out[r*Cv + c] = acc;
    }
}

// ---------------- Y[M,N] = X[M,K] * W[N,K]^T (f32) ----------------
#define GBM 64
#define GBN 64
#define GBK 16
#define GLD 68

__global__ __launch_bounds__(256) void gemm_xwT_kernel(
    const float* __restrict__ X, const float* __restrict__ W, float* __restrict__ Y,
    int M, int N, int K)
{
    __shared__ float Xs[GBK][GLD];
    __shared__ float Ws[GBK][GLD];
    int bm = blockIdx.y * GBM;
    int bn = blockIdx.x * GBN;
    int tid = threadIdx.x;
    int tx = tid & 15, ty = tid >> 4;
    float acc[4][4] = {{0.f}};
    for (int k0 = 0; k0 < K; k0 += GBK) {
#pragma unroll
        for (int i=0;i<4;++i) {
            int idx = tid + i*256;
            int r = idx >> 4, c = idx & 15;
            Xs[c][r] = X[(size_t)(bm + r)*K + k0 + c];
            Ws[c][r] = W[(size_t)(bn + r)*K + k0 + c];
        }
        __syncthreads();
#pragma unroll
        for (int kk=0; kk<GBK; ++kk) {
            float4 a4 = *(const float4*)&Xs[kk][ty*4];
            float4 b4 = *(const float4*)&Ws[kk][tx*4];
            float a[4] = {a4.x,a4.y,a4.z,a4.w};
            float b[4] = {b4.x,b4.y,b4.z,b4.w};
#pragma unroll
            for (int i=0;i<4;++i)
#pragma unroll
                for (int j=0;j<4;++j) acc[i][j] += a[i]*b[j];
        }
        __syncthreads();
    }
#pragma unroll
    for (int i=0;i<4;++i)
#pragma unroll
        for (int j=0;j<4;++j)
            Y[(size_t)(bm + ty*4 + i)*N + bn + tx*4 + j] = acc[i][j];
}

// ---------------- gates + RoPE + RMS-norm + k time-shift -> bf16 [b,h,t,d] ----------------
__global__ __launch_bounds__(256) void post_kernel(
    const float* __restrict__ x, const float* __restrict__ ve,
    const float* __restrict__ cosT, const float* __restrict__ sinT,
    const float* __restrict__ vegw, const float* __restrict__ atgw,
    const float* __restrict__ qf, const float* __restrict__ kraw,
    float* __restrict__ v, float* __restrict__ gateA,
    unsigned short* __restrict__ qbf, unsigned short* __restrict__ kbf)
{
    int bt = blockIdx.x;
    int b = bt >> 11;          // T = 2048
    int t = bt & (Tv-1);
    int wave = threadIdx.x >> 6;
    int lane = threadIdx.x & 63;
    int h = blockIdx.y*4 + wave;
    int base = bt*Cv + h*DHv;
    size_t bh = (size_t)b*Hv + h;

    float gv  = (lane < 32) ? x[bt*Cv + lane] * vegw[h*32 + lane] : 0.f;
    float gaP = (lane < 12) ? x[bt*Cv + lane] * atgw[h*12 + lane] : 0.f;
#pragma unroll
    for (int off=32; off; off>>=1) {
        gv  += __shfl_xor(gv,  off);
        gaP += __shfl_xor(gaP, off);
    }
    float gateV = 2.f / (1.f + expf(-gv));
    float ga    = 1.f / (1.f + expf(-gaP));
    if (lane == 0) gateA[bt*Hv + h] = ga;

    v[base+lane] = v[base+lane] + gateV * ve[base+lane];

    float cs = cosT[t*32 + (lane & 31)];
    float sn = sinT[t*32 + (lane & 31)];

    // q: rope + rms
    float qa = qf[base+lane];
    float qb = __shfl_xor(qa, 32);
    float qr = qa*cs + ((lane < 32) ? qb*sn : -qb*sn);
    float ss = qr*qr;
#pragma unroll
    for (int off=32; off; off>>=1) ss += __shfl_xor(ss, off);
    float qn = qr * rsqrtf(ss*(1.f/64.f) + 1e-6f);
    qbf[(bh*Tv + t)*DHv + lane] = f2bf(qn);

    // k: rope + rms + time-shift of upper half
    float ka = kraw[base+lane];
    float kb = __shfl_xor(ka, 32);
    float kr = ka*cs + ((lane < 32) ? kb*sn : -kb*sn);
    float s2 = kr*kr;
#pragma unroll
    for (int off=32; off; off>>=1) s2 += __shfl_xor(s2, off);
    float kn = kr * rsqrtf(s2*(1.f/64.f) + 1e-6f);
    if (lane < 32) {
        kbf[(bh*Tv + t)*DHv + lane] = f2bf(kn);
    } else {
        if (t == 0)   kbf[(bh*Tv + 0)*DHv + lane] = f2bf(kn);
        if (t+1 < Tv) kbf[(bh*Tv + t + 1)*DHv + lane] = f2bf(kn);
    }
}

// ---------------- V transpose: f32 [b,t,h,d] -> bf16 [b,h,d,t] ----------------
__global__ __launch_bounds__(256) void vt_kernel(
    const float* __restrict__ v, unsigned short* __restrict__ vT)
{
    __shared__ float Ls[64][65];
    int t0 = blockIdx.x * 64;
    int h  = blockIdx.y;
    int b  = blockIdx.z;
    int tid = threadIdx.x;
    for (int i = tid; i < 4096; i += 256) {
        int tt = i >> 6, d = i & 63;
        Ls[tt][d] = v[((size_t)(b*Tv + t0 + tt))*Cv + h*DHv + d];
    }
    __syncthreads();
    size_t ob = ((size_t)(b*Hv + h))*DHv;
    for (int i = tid; i < 4096; i += 256) {
        int dv = i >> 6, tt = i & 63;
        vT[(ob + dv)*Tv + t0 + tt] = f2bf(Ls[tt][dv]);
    }
}

// ---------------- MFMA flash attention ----------------
// block = (qtile of 64 rows, h, b); 4 waves x 16 q-rows; no barriers.
__global__ __launch_bounds__(256) void attn_mfma_kernel(
    const unsigned short* __restrict__ qbf, const unsigned short* __restrict__ kbf,
    const unsigned short* __restrict__ vT, const float* __restrict__ gateA,
    float* __restrict__ y, const int* __restrict__ wptr)
{
    __shared__ __align__(16) short Pl[4][16][72];   // per-wave P transpose buffer

    int qtile = blockIdx.x, h = blockIdx.y, b = blockIdx.z;
    int tid = threadIdx.x, wv = tid >> 6, lane = tid & 63;
    int c = lane & 15, g = lane >> 4;
    int qbase = qtile*64 + wv*16;
    int wsz = *wptr;
    bool use_w = !(wsz < 0 || wsz >= Tv-1);

    size_t bh = (size_t)b*Hv + h;
    const unsigned short* qb = qbf + (bh*Tv + qbase)*DHv;
    short8 A0 = *(const short8*)(qb + (size_t)c*DHv + g*8);
    short8 A1 = *(const short8*)(qb + (size_t)c*DHv + 32 + g*8);

    f32x4 zero4 = {0.f,0.f,0.f,0.f};
    f32x4 O[4];
    float m[4], l[4];
#pragma unroll
    for (int i=0;i<4;++i){ O[i] = zero4; m[i] = -1e30f; l[i] = 0.f; }

    int kt_lo = 0;
    if (use_w) { int lo = qbase - wsz; if (lo < 0) lo = 0; kt_lo = lo >> 6; }
    int kt_hi = qtile;
    const float scale = 0.125f;

    for (int kt = kt_lo; kt <= kt_hi; ++kt) {
        // ---- K fragments (direct global, 16B/lane each) ----
        const unsigned short* kb = kbf + (bh*Tv + (size_t)kt*64)*DHv;
        short8 B0[4], B1[4];
#pragma unroll
        for (int kg=0; kg<4; ++kg) {
            const unsigned short* kr = kb + (size_t)(kg*16 + c)*DHv + g*8;
            B0[kg] = *(const short8*)(kr);
            B1[kg] = *(const short8*)(kr + 32);
        }
        // ---- S = Q K^T ----
        f32x4 S[4];
#pragma unroll
        for (int kg=0; kg<4; ++kg) {
            S[kg] = __builtin_amdgcn_mfma_f32_16x16x32_bf16(A0, B0[kg], zero4, 0,0,0);
            S[kg] = __builtin_amdgcn_mfma_f32_16x16x32_bf16(A1, B1[kg], S[kg], 0,0,0);
        }
        // ---- scale + mask ----
        bool needmask = (kt*64 + 63 > qbase) || (use_w && (kt*64 < qbase + 15 - wsz));
#pragma unroll
        for (int kg=0; kg<4; ++kg)
#pragma unroll
            for (int r=0;r<4;++r) {
                float sv = S[kg][r] * scale;
                if (needmask) {
                    int key = kt*64 + kg*16 + c;
                    int qg  = qbase + g*4 + r;
                    bool ok = (key <= qg) && (!use_w || (qg - key <= wsz));
                    sv = ok ? sv : -1e30f;
                }
                S[kg][r] = sv;
            }
        // ---- online softmax (rows live in 16-lane groups) ----
        float alpha[4];
#pragma unroll
        for (int r=0;r<4;++r) {
            float mx = fmaxf(fmaxf(S[0][r],S[1][r]), fmaxf(S[2][r],S[3][r]));
#pragma unroll
            for (int off=1; off<16; off<<=1) mx = fmaxf(mx, __shfl_xor(mx, off));
            float mn = fmaxf(m[r], mx);
            alpha[r] = __expf(m[r] - mn);   // m<=mn, both -1e30 -> exp(0)=1 (l still 0)
            m[r] = mn;
        }
        float psum[4] = {0.f,0.f,0.f,0.f};
#pragma unroll
        for (int kg=0; kg<4; ++kg)
#pragma unroll
            for (int r=0;r<4;++r) {
                float sv = S[kg][r];
                float pj = (sv > -0.5e30f) ? __expf(sv - m[r]) : 0.f;
                psum[r] += pj;
                Pl[wv][g*4 + r][kg*16 + c] = (short)f2bf(pj);
            }
#pragma unroll
        for (int r=0;r<4;++r) {
#pragma unroll
            for (int off=1; off<16; off<<=1) psum[r] += __shfl_xor(psum[r], off);
            l[r] = l[r]*alpha[r] + psum[r];
        }
        __threadfence_block();   // order cross-lane P writes before vector reads
        short8 PA0 = *(const short8*)(&Pl[wv][c][g*8]);
        short8 PA1 = *(const short8*)(&Pl[wv][c][32 + g*8]);
        // ---- O = O*alpha + P V ----
        const unsigned short* vb = vT + bh*DHv*Tv + (size_t)kt*64;
#pragma unroll
        for (int dg=0; dg<4; ++dg) {
#pragma unroll
            for (int r=0;r<4;++r) O[dg][r] *= alpha[r];
            const unsigned short* vr = vb + (size_t)(dg*16 + c)*Tv + g*8;
            short8 V0 = *(const short8*)(vr);
            short8 V1 = *(const short8*)(vr + 32);
            O[dg] = __builtin_amdgcn_mfma_f32_16x16x32_bf16(PA0, V0, O[dg], 0,0,0);
            O[dg] = __builtin_amdgcn_mfma_f32_16x16x32_bf16(PA1, V1, O[dg], 0,0,0);
        }
    }

    float ga[4], linv[4];
#pragma unroll
    for (int r=0;r<4;++r) {
        ga[r]   = gateA[(size_t)(b*Tv + qbase + g*4 + r)*Hv + h];
        linv[r] = 1.f / l[r];
    }
#pragma unroll
    for (int dg=0; dg<4; ++dg)
#pragma unroll
        for (int r=0;r<4;++r)
            y[((size_t)(b*Tv + qbase + g*4 + r))*Cv + h*DHv + dg*16 + c] =
                O[dg][r] * linv[r] * ga[r];
}

extern "C" void kernel_launch(void* const* d_in, const int* in_sizes, int n_in,
                              void* d_out, int out_size, void* d_ws, size_t ws_size,
                              hipStream_t stream) {
    const float* x    = (const float*)d_in[0];
    const float* ve   = (const float*)d_in[1];
    const float* cosT = (const float*)d_in[2];
    const float* sinT = (const float*)d_in[3];
    const float* cqw  = (const float*)d_in[4];
    const float* ckw  = (const float*)d_in[5];
    const float* cvw  = (const float*)d_in[6];
    const float* cpw  = (const float*)d_in[7];
    const float* vegw = (const float*)d_in[8];
    const float* atgw = (const float*)d_in[9];
    const float* qmix = (const float*)d_in[10];
    const float* kmix = (const float*)d_in[11];
    const float* vmix = (const float*)d_in[12];
    const int*   wsz  = (const int*)d_in[13];
    float* out = (float*)d_out;

    float* p  = (float*)d_ws;
    float* qw = p; p += Cv*Cv;
    float* kw = p; p += Cv*Cv;
    float* vw = p; p += Cv*Cv;
    float* qf = p; p += (size_t)BTv*Cv;
    float* kry= p; p += (size_t)BTv*Cv;   // k-raw, later reused as attention output y
    float* v  = p; p += (size_t)BTv*Cv;
    float* ga = p; p += (size_t)BTv*Hv;
    unsigned short* qbf = (unsigned short*)p; p += (size_t)BTv*Cv/2;
    unsigned short* kbf = (unsigned short*)p; p += (size_t)BTv*Cv/2;
    unsigned short* vT  = (unsigned short*)qw;   // weights dead after QKV GEMMs (8MB < 12MB)

    fuse_w_kernel<<<3*Cv, 256, 0, stream>>>(cqw, ckw, cvw, qmix, kmix, vmix, qw, kw, vw);

    dim3 ggrid(Cv/GBN, BTv/GBM);
    gemm_xwT_kernel<<<ggrid, 256, 0, stream>>>(x, qw, qf,  BTv, Cv, Cv);
    gemm_xwT_kernel<<<ggrid, 256, 0, stream>>>(x, kw, kry, BTv, Cv, Cv);
    gemm_xwT_kernel<<<ggrid, 256, 0, stream>>>(x, vw, v,   BTv, Cv, Cv);

    post_kernel<<<dim3(BTv, Hv/4), 256, 0, stream>>>(x, ve, cosT, sinT, vegw, atgw,
                                                     qf, kry, v, ga, qbf, kbf);

    vt_kernel<<<dim3(Tv/64, Hv, Bv), 256, 0, stream>>>(v, vT);

    attn_mfma_kernel<<<dim3(Tv/64, Hv, Bv), 256, 0, stream>>>(qbf, kbf, vT, ga, kry, wsz);

    gemm_xwT_kernel<<<ggrid, 256, 0, stream>>>(kry, cpw, out, BTv, Cv, Cv);
}

// Round 4
// 433.640 us; speedup vs baseline: 4.4342x; 2.0335x over previous
//
#include <hip/hip_runtime.h>
#include <hip/hip_bf16.h>
#include <math.h>

#define Bv 2
#define Tv 2048
#define Cv 1024
#define Hv 16
#define DHv 64
#define BTv (Bv*Tv)

typedef unsigned short u16;
typedef unsigned int u32;
typedef __attribute__((ext_vector_type(8))) short short8;
typedef __attribute__((ext_vector_type(4))) float f32x4;

__device__ __forceinline__ u16 f2bf(float f) {
    union { float f; unsigned u; } x; x.f = f;
    unsigned r = x.u + 0x7fffu + ((x.u >> 16) & 1u);
    return (u16)(r >> 16);
}

// ---------------- fuse mix into weights -> bf16 [3072][1024]; sel==3: proj w -> bf16 ----------------
__global__ __launch_bounds__(256) void fuse_w_kernel(
    const float* __restrict__ wq, const float* __restrict__ wk, const float* __restrict__ wv,
    const float* __restrict__ wp,
    const float* __restrict__ mq, const float* __restrict__ mk, const float* __restrict__ mv,
    u16* __restrict__ whi, u16* __restrict__ cpj)
{
    int row = blockIdx.x;           // 0 .. 4*C-1
    int sel = row >> 10;
    int r   = row & (Cv-1);
    if (sel == 3) {
        for (int c = threadIdx.x; c < Cv; c += 256)
            cpj[(size_t)r*Cv + c] = f2bf(wp[(size_t)r*Cv + c]);
        return;
    }
    int h = r / DHv, d = r % DHv;
    const float* w   = sel==0 ? wq : (sel==1 ? wk : wv);
    const float* mix = sel==0 ? mq : (sel==1 ? mk : mv);
    float mrow[Hv];
#pragma unroll
    for (int m=0;m<Hv;++m) mrow[m] = mix[h*Hv + m];
    for (int c = threadIdx.x; c < Cv; c += 256) {
        float acc = 0.f;
#pragma unroll
        for (int m=0;m<Hv;++m) acc += mrow[m] * w[(size_t)(m*DHv + d)*Cv + c];
        whi[(size_t)row*Cv + c] = f2bf(acc);
    }
}

// ---------------- x -> bf16 ----------------
__global__ __launch_bounds__(256) void xcvt_kernel(const float* __restrict__ xf, u16* __restrict__ xb)
{
    int i = blockIdx.x*256 + threadIdx.x;     // i < BTv*Cv/4
    float4 v = ((const float4*)xf)[i];
    u32 lo = (u32)f2bf(v.x) | ((u32)f2bf(v.y) << 16);
    u32 hi = (u32)f2bf(v.z) | ((u32)f2bf(v.w) << 16);
    ((uint2*)xb)[i] = make_uint2(lo, hi);
}

// ---------------- bf16 MFMA GEMM: Y[M,N] = X[M,K] * W[N,K]^T, f32 out ----------------
// 256 thr = 4 waves (2x2), BK=32, XOR slot-swizzled LDS (2-way banks on write & b128 read)
template<int BM, int BN>
__global__ __launch_bounds__(256) void gemm_bf16_kernel(
    const u16* __restrict__ X, const u16* __restrict__ W, float* __restrict__ Y,
    int M, int N, int K)
{
    constexpr int MR = BM/32, NR = BN/32;
    __shared__ __align__(16) u16 As[BM*32];
    __shared__ __align__(16) u16 Bs[BN*32];
    int tid = threadIdx.x;
    int w = tid >> 6, lane = tid & 63;
    int wr = w >> 1, wc = w & 1;
    int c = lane & 15, g = lane >> 4;
    int bm = blockIdx.y * BM, bn = blockIdx.x * BN;

    f32x4 acc[MR][NR];
#pragma unroll
    for (int i=0;i<MR;++i)
#pragma unroll
        for (int j=0;j<NR;++j) acc[i][j] = (f32x4){0.f,0.f,0.f,0.f};

    int srow = tid >> 2, ss = tid & 3;

    for (int k0 = 0; k0 < K; k0 += 32) {
#pragma unroll
        for (int p=0; p<BM/64; ++p) {
            int row = p*64 + srow;
            int slot = ss ^ ((row>>1)&3);
            *(short8*)&As[row*32 + slot*8] =
                *(const short8*)&X[(size_t)(bm+row)*K + k0 + ss*8];
        }
#pragma unroll
        for (int p=0; p<BN/64; ++p) {
            int row = p*64 + srow;
            int slot = ss ^ ((row>>1)&3);
            *(short8*)&Bs[row*32 + slot*8] =
                *(const short8*)&W[(size_t)(bn+row)*K + k0 + ss*8];
        }
        __syncthreads();
        short8 a[MR], bf[NR];
#pragma unroll
        for (int i=0;i<MR;++i) {
            int row = wr*(BM/2) + i*16 + c;
            a[i] = *(const short8*)&As[row*32 + (g ^ ((row>>1)&3))*8];
        }
#pragma unroll
        for (int j=0;j<NR;++j) {
            int row = wc*(BN/2) + j*16 + c;
            bf[j] = *(const short8*)&Bs[row*32 + (g ^ ((row>>1)&3))*8];
        }
#pragma unroll
        for (int i=0;i<MR;++i)
#pragma unroll
            for (int j=0;j<NR;++j)
                acc[i][j] = __builtin_amdgcn_mfma_f32_16x16x32_bf16(a[i], bf[j], acc[i][j], 0,0,0);
        __syncthreads();
    }
#pragma unroll
    for (int i=0;i<MR;++i)
#pragma unroll
        for (int j=0;j<NR;++j)
#pragma unroll
            for (int r=0;r<4;++r)
                Y[(size_t)(bm + wr*(BM/2) + i*16 + g*4 + r)*N + bn + wc*(BN/2) + j*16 + c] = acc[i][j][r];
}

// ---------------- gates + RoPE + RMS-norm + k time-shift -> bf16 [b,h,t,d] ----------------
// qkv: [BT][3072] f32 (cols 0..1023 q, 1024.. k, 2048.. v); v gated in place
__global__ __launch_bounds__(256) void post_kernel(
    const float* __restrict__ x, const float* __restrict__ ve,
    const float* __restrict__ cosT, const float* __restrict__ sinT,
    const float* __restrict__ vegw, const float* __restrict__ atgw,
    float* __restrict__ qkv, float* __restrict__ gateA,
    u16* __restrict__ qbf, u16* __restrict__ kbf)
{
    int bt = blockIdx.x;
    int b = bt >> 11;
    int t = bt & (Tv-1);
    int wave = threadIdx.x >> 6;
    int lane = threadIdx.x & 63;
    int h = blockIdx.y*4 + wave;
    size_t base = (size_t)bt*3072 + h*DHv;
    size_t bh = (size_t)b*Hv + h;

    float gv  = (lane < 32) ? x[(size_t)bt*Cv + lane] * vegw[h*32 + lane] : 0.f;
    float gaP = (lane < 12) ? x[(size_t)bt*Cv + lane] * atgw[h*12 + lane] : 0.f;
#pragma unroll
    for (int off=32; off; off>>=1) {
        gv  += __shfl_xor(gv,  off);
        gaP += __shfl_xor(gaP, off);
    }
    float gateV = 2.f / (1.f + expf(-gv));
    float ga    = 1.f / (1.f + expf(-gaP));
    if (lane == 0) gateA[(size_t)bt*Hv + h] = ga;

    qkv[base + 2048 + lane] += gateV * ve[(size_t)bt*Cv + h*DHv + lane];

    float cs = cosT[t*32 + (lane & 31)];
    float sn = sinT[t*32 + (lane & 31)];

    // q: rope + rms
    float qa = qkv[base + lane];
    float qb = __shfl_xor(qa, 32);
    float qr = qa*cs + ((lane < 32) ? qb*sn : -qb*sn);
    float ss = qr*qr;
#pragma unroll
    for (int off=32; off; off>>=1) ss += __shfl_xor(ss, off);
    float qn = qr * rsqrtf(ss*(1.f/64.f) + 1e-6f);
    qbf[(bh*Tv + t)*DHv + lane] = f2bf(qn);

    // k: rope + rms + time-shift of upper half
    float ka = qkv[base + 1024 + lane];
    float kb = __shfl_xor(ka, 32);
    float kr = ka*cs + ((lane < 32) ? kb*sn : -kb*sn);
    float s2 = kr*kr;
#pragma unroll
    for (int off=32; off; off>>=1) s2 += __shfl_xor(s2, off);
    float kn = kr * rsqrtf(s2*(1.f/64.f) + 1e-6f);
    if (lane < 32) {
        kbf[(bh*Tv + t)*DHv + lane] = f2bf(kn);
    } else {
        if (t == 0)   kbf[(bh*Tv + 0)*DHv + lane] = f2bf(kn);
        if (t+1 < Tv) kbf[(bh*Tv + t + 1)*DHv + lane] = f2bf(kn);
    }
}

// ---------------- V transpose: f32 qkv v-part -> bf16 [b,h,d,t] ----------------
__global__ __launch_bounds__(256) void vt_kernel(
    const float* __restrict__ qkv, u16* __restrict__ vT)
{
    __shared__ float Ls[64][65];
    int t0 = blockIdx.x * 64;
    int h  = blockIdx.y;
    int b  = blockIdx.z;
    int tid = threadIdx.x;
    for (int i = tid; i < 4096; i += 256) {
        int tt = i >> 6, d = i & 63;
        Ls[tt][d] = qkv[((size_t)(b*Tv + t0 + tt))*3072 + 2048 + h*DHv + d];
    }
    __syncthreads();
    size_t ob = ((size_t)(b*Hv + h))*DHv;
    for (int i = tid; i < 4096; i += 256) {
        int dv = i >> 6, tt = i & 63;
        vT[(ob + dv)*Tv + t0 + tt] = f2bf(Ls[tt][dv]);
    }
}

// ---------------- MFMA flash attention: fixed-max softmax, l via ones-MFMA ----------------
__global__ __launch_bounds__(256) void attn_mfma_kernel(
    const u16* __restrict__ qbf, const u16* __restrict__ kbf,
    const u16* __restrict__ vT, const float* __restrict__ gateA,
    u16* __restrict__ ybf, const int* __restrict__ wptr)
{
    __shared__ __align__(16) u16 Pl[4][16][72];

    int qtile = (int)gridDim.x - 1 - (int)blockIdx.x;   // longest-first
    int h = blockIdx.y, b = blockIdx.z;
    int tid = threadIdx.x, wv = tid >> 6, lane = tid & 63;
    int c = lane & 15, g = lane >> 4;
    int qbase = qtile*64 + wv*16;
    int wsz = *wptr;
    bool use_w = !(wsz < 0 || wsz >= Tv-1);

    size_t bh = (size_t)b*Hv + h;
    const u16* qb = qbf + (bh*(size_t)Tv + qbase)*DHv;
    short8 A0 = *(const short8*)(qb + (size_t)c*DHv + g*8);
    short8 A1 = *(const short8*)(qb + (size_t)c*DHv + 32 + g*8);

    f32x4 zero4 = {0.f,0.f,0.f,0.f};
    f32x4 O[4];
    f32x4 L = zero4;
#pragma unroll
    for (int i=0;i<4;++i) O[i] = zero4;

    short8 ONES;
#pragma unroll
    for (int i=0;i<8;++i) ONES[i] = (short)0x3F80;   // bf16 1.0

    int kt_lo = 0;
    if (use_w) { int lo = qbase - wsz; if (lo > 0) kt_lo = lo >> 6; }
    const float scale = 0.125f;   // 1/sqrt(64)

    for (int kt = kt_lo; kt <= qtile; ++kt) {
        const u16* kb = kbf + (bh*(size_t)Tv + (size_t)kt*64)*DHv;
        short8 B0[4], B1[4], V0[4], V1[4];
#pragma unroll
        for (int kg=0; kg<4; ++kg) {
            const u16* kr = kb + (size_t)(kg*16 + c)*DHv + g*8;
            B0[kg] = *(const short8*)(kr);
            B1[kg] = *(const short8*)(kr + 32);
        }
        const u16* vb = vT + bh*(size_t)(DHv*Tv) + (size_t)kt*64;
#pragma unroll
        for (int dg=0; dg<4; ++dg) {
            const u16* vr = vb + (size_t)(dg*16 + c)*Tv + g*8;
            V0[dg] = *(const short8*)(vr);
            V1[dg] = *(const short8*)(vr + 32);
        }
        f32x4 S[4];
#pragma unroll
        for (int kg=0; kg<4; ++kg) {
            S[kg] = __builtin_amdgcn_mfma_f32_16x16x32_bf16(A0, B0[kg], zero4, 0,0,0);
            S[kg] = __builtin_amdgcn_mfma_f32_16x16x32_bf16(A1, B1[kg], S[kg], 0,0,0);
        }
        bool needmask = (kt*64 + 63 > qbase) || (use_w && (kt*64 < qbase + 15 - wsz));
#pragma unroll
        for (int kg=0; kg<4; ++kg)
#pragma unroll
            for (int r=0;r<4;++r) {
                float sv = S[kg][r] * scale;
                if (needmask) {
                    int key = kt*64 + kg*16 + c;
                    int qg  = qbase + g*4 + r;
                    bool ok = (key <= qg) && (!use_w || (qg - key <= wsz));
                    sv = ok ? sv : -1e30f;
                }
                float pj = __expf(sv - 8.0f);   // |s|<=8.07 => p in (0, 1.07]
                Pl[wv][g*4 + r][kg*16 + c] = f2bf(pj);
            }
        __threadfence_block();   // order cross-lane P writes before vector reads
        short8 PA0 = *(const short8*)(&Pl[wv][c][g*8]);
        short8 PA1 = *(const short8*)(&Pl[wv][c][32 + g*8]);
        L = __builtin_amdgcn_mfma_f32_16x16x32_bf16(PA0, ONES, L, 0,0,0);
        L = __builtin_amdgcn_mfma_f32_16x16x32_bf16(PA1, ONES, L, 0,0,0);
#pragma unroll
        for (int dg=0; dg<4; ++dg) {
            O[dg] = __builtin_amdgcn_mfma_f32_16x16x32_bf16(PA0, V0[dg], O[dg], 0,0,0);
            O[dg] = __builtin_amdgcn_mfma_f32_16x16x32_bf16(PA1, V1[dg], O[dg], 0,0,0);
        }
    }

    float gar[4], linv[4];
#pragma unroll
    for (int r=0;r<4;++r) {
        gar[r]  = gateA[(size_t)(b*Tv + qbase + g*4 + r)*Hv + h];
        linv[r] = 1.f / L[r];
    }
#pragma unroll
    for (int dg=0; dg<4; ++dg)
#pragma unroll
        for (int r=0;r<4;++r)
            ybf[((size_t)(b*Tv + qbase + g*4 + r))*Cv + h*DHv + dg*16 + c] =
                f2bf(O[dg][r] * linv[r] * gar[r]);
}

extern "C" void kernel_launch(void* const* d_in, const int* in_sizes, int n_in,
                              void* d_out, int out_size, void* d_ws, size_t ws_size,
                              hipStream_t stream) {
    const float* x    = (const float*)d_in[0];
    const float* ve   = (const float*)d_in[1];
    const float* cosT = (const float*)d_in[2];
    const float* sinT = (const float*)d_in[3];
    const float* cqw  = (const float*)d_in[4];
    const float* ckw  = (const float*)d_in[5];
    const float* cvw  = (const float*)d_in[6];
    const float* cpw  = (const float*)d_in[7];
    const float* vegw = (const float*)d_in[8];
    const float* atgw = (const float*)d_in[9];
    const float* qmix = (const float*)d_in[10];
    const float* kmix = (const float*)d_in[11];
    const float* vmix = (const float*)d_in[12];
    const int*   wsz  = (const int*)d_in[13];
    float* out = (float*)d_out;

    const size_t M1 = 1u << 20;
    float* p0 = (float*)d_ws;
    // layout (float units): [0,12M) qkv f32 | [12M,12.5M) cpj bf16 | [12.5M,12.57M) ga
    // | [13M,15M) qbf | [15M,17M) kbf | [17M,19M) vT   (total 76 MB)
    // phase-A aliases: whi bf16 at [13M,14.5M); xbf bf16 at [15M,17M)
    // phase-C alias:   ybf bf16 at [0,2M)
    float* qkv = p0;
    u16*   cpj = (u16*)(p0 + 12*M1);
    float* ga  = p0 + 12*M1 + M1/2;
    u16*   qbf = (u16*)(p0 + 13*M1);
    u16*   kbf = (u16*)(p0 + 15*M1);
    u16*   vT  = (u16*)(p0 + 17*M1);
    u16*   whi = (u16*)(p0 + 13*M1);
    u16*   xbf = (u16*)(p0 + 15*M1);
    u16*   ybf = (u16*)p0;

    fuse_w_kernel<<<4*Cv, 256, 0, stream>>>(cqw, ckw, cvw, cpw, qmix, kmix, vmix, whi, cpj);
    xcvt_kernel<<<(BTv*Cv/4)/256, 256, 0, stream>>>(x, xbf);

    gemm_bf16_kernel<128,128><<<dim3(3072/128, BTv/128), 256, 0, stream>>>(
        xbf, whi, qkv, BTv, 3072, Cv);

    post_kernel<<<dim3(BTv, Hv/4), 256, 0, stream>>>(x, ve, cosT, sinT, vegw, atgw,
                                                     qkv, ga, qbf, kbf);

    vt_kernel<<<dim3(Tv/64, Hv, Bv), 256, 0, stream>>>(qkv, vT);

    attn_mfma_kernel<<<dim3(Tv/64, Hv, Bv), 256, 0, stream>>>(qbf, kbf, vT, ga, ybf, wsz);

    gemm_bf16_kernel<64,128><<<dim3(Cv/128, BTv/64), 256, 0, stream>>>(
        ybf, cpj, out, BTv, Cv, Cv);
}

// Round 5
// 297.754 us; speedup vs baseline: 6.4579x; 1.4564x over previous
//
#include <hip/hip_runtime.h>
#include <hip/hip_bf16.h>
#include <math.h>

#define Bv 2
#define Tv 2048
#define Cv 1024
#define Hv 16
#define DHv 64
#define BTv (Bv*Tv)

typedef unsigned short u16;
typedef unsigned int u32;
typedef __attribute__((ext_vector_type(8))) short short8;
typedef __attribute__((ext_vector_type(4))) float f32x4;

__device__ __forceinline__ u16 f2bf(float f) {
    union { float f; unsigned u; } x; x.f = f;
    unsigned r = x.u + 0x7fffu + ((x.u >> 16) & 1u);
    return (u16)(r >> 16);
}

// ---------------- fuse mix into weights -> bf16 [3072][1024]; sel==3: proj w -> bf16 ----------------
__global__ __launch_bounds__(256) void fuse_w_kernel(
    const float* __restrict__ wq, const float* __restrict__ wk, const float* __restrict__ wv,
    const float* __restrict__ wp,
    const float* __restrict__ mq, const float* __restrict__ mk, const float* __restrict__ mv,
    u16* __restrict__ whi, u16* __restrict__ cpj)
{
    int row = blockIdx.x;           // 0 .. 4*C-1
    int sel = row >> 10;
    int r   = row & (Cv-1);
    if (sel == 3) {
        for (int c = threadIdx.x; c < Cv; c += 256)
            cpj[(size_t)r*Cv + c] = f2bf(wp[(size_t)r*Cv + c]);
        return;
    }
    int h = r / DHv, d = r % DHv;
    const float* w   = sel==0 ? wq : (sel==1 ? wk : wv);
    const float* mix = sel==0 ? mq : (sel==1 ? mk : mv);
    float mrow[Hv];
#pragma unroll
    for (int m=0;m<Hv;++m) mrow[m] = mix[h*Hv + m];
    for (int c = threadIdx.x; c < Cv; c += 256) {
        float acc = 0.f;
#pragma unroll
        for (int m=0;m<Hv;++m) acc += mrow[m] * w[(size_t)(m*DHv + d)*Cv + c];
        whi[(size_t)row*Cv + c] = f2bf(acc);
    }
}

// ---------------- x -> bf16 ----------------
__global__ __launch_bounds__(256) void xcvt_kernel(const float* __restrict__ xf, u16* __restrict__ xb)
{
    int i = blockIdx.x*256 + threadIdx.x;     // i < BTv*Cv/4
    float4 v = ((const float4*)xf)[i];
    u32 lo = (u32)f2bf(v.x) | ((u32)f2bf(v.y) << 16);
    u32 hi = (u32)f2bf(v.z) | ((u32)f2bf(v.w) << 16);
    ((uint2*)xb)[i] = make_uint2(lo, hi);
}

// ---------------- bf16 MFMA GEMM: Y[M,N] = X[M,K] * W[N,K]^T, f32 out ----------------
template<int BM, int BN>
__global__ __launch_bounds__(256) void gemm_bf16_kernel(
    const u16* __restrict__ X, const u16* __restrict__ W, float* __restrict__ Y,
    int M, int N, int K)
{
    constexpr int MR = BM/32, NR = BN/32;
    __shared__ __align__(16) u16 As[BM*32];
    __shared__ __align__(16) u16 Bs[BN*32];
    int tid = threadIdx.x;
    int w = tid >> 6, lane = tid & 63;
    int wr = w >> 1, wc = w & 1;
    int c = lane & 15, g = lane >> 4;
    int bm = blockIdx.y * BM, bn = blockIdx.x * BN;

    f32x4 acc[MR][NR];
#pragma unroll
    for (int i=0;i<MR;++i)
#pragma unroll
        for (int j=0;j<NR;++j) acc[i][j] = (f32x4){0.f,0.f,0.f,0.f};

    int srow = tid >> 2, ss = tid & 3;

    for (int k0 = 0; k0 < K; k0 += 32) {
#pragma unroll
        for (int p=0; p<BM/64; ++p) {
            int row = p*64 + srow;
            int slot = ss ^ ((row>>1)&3);
            *(short8*)&As[row*32 + slot*8] =
                *(const short8*)&X[(size_t)(bm+row)*K + k0 + ss*8];
        }
#pragma unroll
        for (int p=0; p<BN/64; ++p) {
            int row = p*64 + srow;
            int slot = ss ^ ((row>>1)&3);
            *(short8*)&Bs[row*32 + slot*8] =
                *(const short8*)&W[(size_t)(bn+row)*K + k0 + ss*8];
        }
        __syncthreads();
        short8 a[MR], bf[NR];
#pragma unroll
        for (int i=0;i<MR;++i) {
            int row = wr*(BM/2) + i*16 + c;
            a[i] = *(const short8*)&As[row*32 + (g ^ ((row>>1)&3))*8];
        }
#pragma unroll
        for (int j=0;j<NR;++j) {
            int row = wc*(BN/2) + j*16 + c;
            bf[j] = *(const short8*)&Bs[row*32 + (g ^ ((row>>1)&3))*8];
        }
#pragma unroll
        for (int i=0;i<MR;++i)
#pragma unroll
            for (int j=0;j<NR;++j)
                acc[i][j] = __builtin_amdgcn_mfma_f32_16x16x32_bf16(a[i], bf[j], acc[i][j], 0,0,0);
        __syncthreads();
    }
#pragma unroll
    for (int i=0;i<MR;++i)
#pragma unroll
        for (int j=0;j<NR;++j)
#pragma unroll
            for (int r=0;r<4;++r)
                Y[(size_t)(bm + wr*(BM/2) + i*16 + g*4 + r)*N + bn + wc*(BN/2) + j*16 + c] = acc[i][j][r];
}

// ---------------- gates + RoPE + RMS-norm + k time-shift -> bf16 [b,h,t,d] ----------------
__global__ __launch_bounds__(256) void post_kernel(
    const float* __restrict__ x, const float* __restrict__ ve,
    const float* __restrict__ cosT, const float* __restrict__ sinT,
    const float* __restrict__ vegw, const float* __restrict__ atgw,
    float* __restrict__ qkv, float* __restrict__ gateA,
    u16* __restrict__ qbf, u16* __restrict__ kbf)
{
    int bt = blockIdx.x;
    int b = bt >> 11;
    int t = bt & (Tv-1);
    int wave = threadIdx.x >> 6;
    int lane = threadIdx.x & 63;
    int h = blockIdx.y*4 + wave;
    size_t base = (size_t)bt*3072 + h*DHv;
    size_t bh = (size_t)b*Hv + h;

    float gv  = (lane < 32) ? x[(size_t)bt*Cv + lane] * vegw[h*32 + lane] : 0.f;
    float gaP = (lane < 12) ? x[(size_t)bt*Cv + lane] * atgw[h*12 + lane] : 0.f;
#pragma unroll
    for (int off=32; off; off>>=1) {
        gv  += __shfl_xor(gv,  off);
        gaP += __shfl_xor(gaP, off);
    }
    float gateV = 2.f / (1.f + expf(-gv));
    float ga    = 1.f / (1.f + expf(-gaP));
    if (lane == 0) gateA[(size_t)bt*Hv + h] = ga;

    qkv[base + 2048 + lane] += gateV * ve[(size_t)bt*Cv + h*DHv + lane];

    float cs = cosT[t*32 + (lane & 31)];
    float sn = sinT[t*32 + (lane & 31)];

    // q: rope + rms
    float qa = qkv[base + lane];
    float qb = __shfl_xor(qa, 32);
    float qr = qa*cs + ((lane < 32) ? qb*sn : -qb*sn);
    float ss = qr*qr;
#pragma unroll
    for (int off=32; off; off>>=1) ss += __shfl_xor(ss, off);
    float qn = qr * rsqrtf(ss*(1.f/64.f) + 1e-6f);
    qbf[(bh*Tv + t)*DHv + lane] = f2bf(qn);

    // k: rope + rms + time-shift of upper half
    float ka = qkv[base + 1024 + lane];
    float kb = __shfl_xor(ka, 32);
    float kr = ka*cs + ((lane < 32) ? kb*sn : -kb*sn);
    float s2 = kr*kr;
#pragma unroll
    for (int off=32; off; off>>=1) s2 += __shfl_xor(s2, off);
    float kn = kr * rsqrtf(s2*(1.f/64.f) + 1e-6f);
    if (lane < 32) {
        kbf[(bh*Tv + t)*DHv + lane] = f2bf(kn);
    } else {
        if (t == 0)   kbf[(bh*Tv + 0)*DHv + lane] = f2bf(kn);
        if (t+1 < Tv) kbf[(bh*Tv + t + 1)*DHv + lane] = f2bf(kn);
    }
}

// ---------------- V transpose: f32 qkv v-part -> bf16 [b,h,d,t] ----------------
__global__ __launch_bounds__(256) void vt_kernel(
    const float* __restrict__ qkv, u16* __restrict__ vT)
{
    __shared__ float Ls[64][65];
    int t0 = blockIdx.x * 64;
    int h  = blockIdx.y;
    int b  = blockIdx.z;
    int tid = threadIdx.x;
    for (int i = tid; i < 4096; i += 256) {
        int tt = i >> 6, d = i & 63;
        Ls[tt][d] = qkv[((size_t)(b*Tv + t0 + tt))*3072 + 2048 + h*DHv + d];
    }
    __syncthreads();
    size_t ob = ((size_t)(b*Hv + h))*DHv;
    for (int i = tid; i < 4096; i += 256) {
        int dv = i >> 6, tt = i & 63;
        vT[(ob + dv)*Tv + t0 + tt] = f2bf(Ls[tt][dv]);
    }
}

// ---------------- MFMA flash attention: LDS-staged K/V, double-buffered, BQ=128 ----------------
// block = 4 waves x 32 q-rows; K tile [64 keys][64 d], Vt tile [64 d][64 keys], XOR-swizzled.
__global__ __launch_bounds__(256) void attn_mfma_kernel(
    const u16* __restrict__ qbf, const u16* __restrict__ kbf,
    const u16* __restrict__ vT, const float* __restrict__ gateA,
    u16* __restrict__ ybf, const int* __restrict__ wptr)
{
    __shared__ __align__(16) u16 Ks[2][64*64];
    __shared__ __align__(16) u16 Vt[2][64*64];
    __shared__ __align__(16) u16 Pl[4][32][88];   // stride 88 u16: 2-way banks on write & read

    int qtile = (int)gridDim.x - 1 - (int)blockIdx.x;   // longest-first
    int h = blockIdx.y, b = blockIdx.z;
    int tid = threadIdx.x, wv = tid >> 6, lane = tid & 63;
    int c = lane & 15, g = lane >> 4;
    int qbase = qtile*128 + wv*32;
    int wsz = *wptr;
    bool use_w = !(wsz < 0 || wsz >= Tv-1);

    size_t bh = (size_t)b*Hv + h;
    const u16* qb = qbf + (bh*(size_t)Tv + qbase)*DHv;
    short8 A[2][2];
#pragma unroll
    for (int rb=0; rb<2; ++rb)
#pragma unroll
        for (int kh=0; kh<2; ++kh)
            A[rb][kh] = *(const short8*)(qb + (size_t)(rb*16+c)*DHv + kh*32 + g*8);

    f32x4 zero4 = {0.f,0.f,0.f,0.f};
    f32x4 O[2][4], L[2];
#pragma unroll
    for (int rb=0;rb<2;++rb){ L[rb]=zero4;
#pragma unroll
        for (int dg=0;dg<4;++dg) O[rb][dg]=zero4; }

    short8 ONES;
#pragma unroll
    for (int i=0;i<8;++i) ONES[i] = (short)0x3F80;   // bf16 1.0

    int kt_hi = qtile*2 + 1;
    int kt_lo = 0;
    if (use_w) { int lo = qtile*128 - wsz; if (lo > 0) kt_lo = lo >> 6; }
    const float scale = 0.125f;

    // staging geometry: 512 K-chunks + 512 V-chunks of 16B; thread does 2 of each
    const u16* gK = kbf + bh*(size_t)Tv*DHv;
    const u16* gV = vT  + bh*(size_t)DHv*Tv;
    int r0 = tid >> 3, sb = tid & 7;     // chunk tid:   row r0      (0..31)
    int r1 = r0 + 32;                    // chunk tid+256: row r0+32 (32..63)
    int lk0 = r0*64 + ((sb ^ (r0&7))*8); // swizzled LDS u16 index
    int lk1 = r1*64 + ((sb ^ (r1&7))*8);
    short8 RK0, RK1, RV0, RV1;

    auto stage_load = [&](int kt) {
        size_t kb0 = (size_t)kt*4096;
        RK0 = *(const short8*)(gK + kb0 + r0*64 + sb*8);
        RK1 = *(const short8*)(gK + kb0 + r1*64 + sb*8);
        RV0 = *(const short8*)(gV + (size_t)r0*Tv + kt*64 + sb*8);
        RV1 = *(const short8*)(gV + (size_t)r1*Tv + kt*64 + sb*8);
    };
    auto stage_write = [&](int buf) {
        *(short8*)&Ks[buf][lk0] = RK0;
        *(short8*)&Ks[buf][lk1] = RK1;
        *(short8*)&Vt[buf][lk0] = RV0;
        *(short8*)&Vt[buf][lk1] = RV1;
    };

    auto compute = [&](int kt, int cur) {
        short8 Bk[4][2];
#pragma unroll
        for (int kg=0;kg<4;++kg)
#pragma unroll
            for (int kh=0;kh<2;++kh)
                Bk[kg][kh] = *(const short8*)&Ks[cur][(kg*16+c)*64 + (((kh*4+g) ^ (c&7))*8)];
        f32x4 S[2][4];
#pragma unroll
        for (int rb=0;rb<2;++rb)
#pragma unroll
            for (int kg=0;kg<4;++kg) {
                S[rb][kg] = __builtin_amdgcn_mfma_f32_16x16x32_bf16(A[rb][0], Bk[kg][0], zero4, 0,0,0);
                S[rb][kg] = __builtin_amdgcn_mfma_f32_16x16x32_bf16(A[rb][1], Bk[kg][1], S[rb][kg], 0,0,0);
            }
        bool needmask = (kt*64 + 63 > qbase) || (use_w && (kt*64 < qbase + 31 - wsz));
#pragma unroll
        for (int rb=0;rb<2;++rb)
#pragma unroll
            for (int kg=0;kg<4;++kg)
#pragma unroll
                for (int r=0;r<4;++r) {
                    float sv = S[rb][kg][r] * scale;
                    if (needmask) {
                        int key = kt*64 + kg*16 + c;
                        int qg  = qbase + rb*16 + g*4 + r;
                        bool ok = (key <= qg) && (!use_w || (qg - key <= wsz));
                        sv = ok ? sv : -1e30f;
                    }
                    Pl[wv][rb*16 + g*4 + r][kg*16 + c] = f2bf(__expf(sv - 8.0f));
                }
        asm volatile("s_waitcnt lgkmcnt(0)" ::: "memory");
        __builtin_amdgcn_sched_barrier(0);
        short8 Vf[4][2];
#pragma unroll
        for (int dg=0;dg<4;++dg)
#pragma unroll
            for (int kh=0;kh<2;++kh)
                Vf[dg][kh] = *(const short8*)&Vt[cur][(dg*16+c)*64 + (((kh*4+g) ^ (c&7))*8)];
#pragma unroll
        for (int rb=0;rb<2;++rb) {
            short8 PA0 = *(const short8*)&Pl[wv][rb*16+c][g*8];
            short8 PA1 = *(const short8*)&Pl[wv][rb*16+c][32 + g*8];
            L[rb] = __builtin_amdgcn_mfma_f32_16x16x32_bf16(PA0, ONES, L[rb], 0,0,0);
            L[rb] = __builtin_amdgcn_mfma_f32_16x16x32_bf16(PA1, ONES, L[rb], 0,0,0);
#pragma unroll
            for (int dg=0;dg<4;++dg) {
                O[rb][dg] = __builtin_amdgcn_mfma_f32_16x16x32_bf16(PA0, Vf[dg][0], O[rb][dg], 0,0,0);
                O[rb][dg] = __builtin_amdgcn_mfma_f32_16x16x32_bf16(PA1, Vf[dg][1], O[rb][dg], 0,0,0);
            }
        }
    };

    // prologue
    stage_load(kt_lo);
    stage_write(0);
    __syncthreads();
    int cur = 0;
    for (int kt = kt_lo; kt <= kt_hi; ++kt) {
        bool more = (kt < kt_hi);
        if (more) stage_load(kt+1);       // global loads in flight during compute
        compute(kt, cur);
        if (more) stage_write(cur^1);
        __syncthreads();
        cur ^= 1;
    }

    float gar[2][4], linv[2][4];
#pragma unroll
    for (int rb=0;rb<2;++rb)
#pragma unroll
        for (int r=0;r<4;++r) {
            gar[rb][r]  = gateA[(size_t)(b*Tv + qbase + rb*16 + g*4 + r)*Hv + h];
            linv[rb][r] = 1.f / L[rb][r];
        }
#pragma unroll
    for (int rb=0;rb<2;++rb)
#pragma unroll
        for (int dg=0;dg<4;++dg)
#pragma unroll
            for (int r=0;r<4;++r)
                ybf[((size_t)(b*Tv + qbase + rb*16 + g*4 + r))*Cv + h*DHv + dg*16 + c] =
                    f2bf(O[rb][dg][r] * linv[rb][r] * gar[rb][r]);
}

extern "C" void kernel_launch(void* const* d_in, const int* in_sizes, int n_in,
                              void* d_out, int out_size, void* d_ws, size_t ws_size,
                              hipStream_t stream) {
    const float* x    = (const float*)d_in[0];
    const float* ve   = (const float*)d_in[1];
    const float* cosT = (const float*)d_in[2];
    const float* sinT = (const float*)d_in[3];
    const float* cqw  = (const float*)d_in[4];
    const float* ckw  = (const float*)d_in[5];
    const float* cvw  = (const float*)d_in[6];
    const float* cpw  = (const float*)d_in[7];
    const float* vegw = (const float*)d_in[8];
    const float* atgw = (const float*)d_in[9];
    const float* qmix = (const float*)d_in[10];
    const float* kmix = (const float*)d_in[11];
    const float* vmix = (const float*)d_in[12];
    const int*   wsz  = (const int*)d_in[13];
    float* out = (float*)d_out;

    const size_t M1 = 1u << 20;
    float* p0 = (float*)d_ws;
    float* qkv = p0;
    u16*   cpj = (u16*)(p0 + 12*M1);
    float* ga  = p0 + 12*M1 + M1/2;
    u16*   qbf = (u16*)(p0 + 13*M1);
    u16*   kbf = (u16*)(p0 + 15*M1);
    u16*   vT  = (u16*)(p0 + 17*M1);
    u16*   whi = (u16*)(p0 + 13*M1);
    u16*   xbf = (u16*)(p0 + 15*M1);
    u16*   ybf = (u16*)p0;

    fuse_w_kernel<<<4*Cv, 256, 0, stream>>>(cqw, ckw, cvw, cpw, qmix, kmix, vmix, whi, cpj);
    xcvt_kernel<<<(BTv*Cv/4)/256, 256, 0, stream>>>(x, xbf);

    gemm_bf16_kernel<128,128><<<dim3(3072/128, BTv/128), 256, 0, stream>>>(
        xbf, whi, qkv, BTv, 3072, Cv);

    post_kernel<<<dim3(BTv, Hv/4), 256, 0, stream>>>(x, ve, cosT, sinT, vegw, atgw,
                                                     qkv, ga, qbf, kbf);

    vt_kernel<<<dim3(Tv/64, Hv, Bv), 256, 0, stream>>>(qkv, vT);

    attn_mfma_kernel<<<dim3(Tv/128, Hv, Bv), 256, 0, stream>>>(qbf, kbf, vT, ga, ybf, wsz);

    gemm_bf16_kernel<64,128><<<dim3(Cv/128, BTv/64), 256, 0, stream>>>(
        ybf, cpj, out, BTv, Cv, Cv);
}

// Round 6
// 297.509 us; speedup vs baseline: 6.4632x; 1.0008x over previous
//
#include <hip/hip_runtime.h>
#include <hip/hip_bf16.h>
#include <math.h>

#define Bv 2
#define Tv 2048
#define Cv 1024
#define Hv 16
#define DHv 64
#define BTv (Bv*Tv)

typedef unsigned short u16;
typedef unsigned int u32;
typedef __attribute__((ext_vector_type(8))) short short8;
typedef __attribute__((ext_vector_type(4))) float f32x4;

#define GLOAD16(g,l) __builtin_amdgcn_global_load_lds((const __attribute__((address_space(1))) void*)(g), (__attribute__((address_space(3))) void*)(l), 16, 0, 0)

__device__ __forceinline__ u16 f2bf(float f) {
    u32 r; asm("v_cvt_pk_bf16_f32 %0, %1, %1" : "=v"(r) : "v"(f)); return (u16)r;
}
__device__ __forceinline__ u32 pk2bf(float a, float b) {
    u32 r; asm("v_cvt_pk_bf16_f32 %0, %1, %2" : "=v"(r) : "v"(a), "v"(b)); return r;
}
__device__ __forceinline__ float fexp2(float x) {
    float r; asm("v_exp_f32 %0, %1" : "=v"(r) : "v"(x)); return r;
}

// ---------------- fuse mix into weights (block per (sel,d)) + proj cvt ----------------
__global__ __launch_bounds__(256) void fuse_w_kernel(
    const float* __restrict__ wq, const float* __restrict__ wk, const float* __restrict__ wv,
    const float* __restrict__ wp,
    const float* __restrict__ mq, const float* __restrict__ mk, const float* __restrict__ mv,
    u16* __restrict__ whi, u16* __restrict__ cpj)
{
    int blk = blockIdx.x;
    int tid = threadIdx.x;
    if (blk >= 192) {          // proj weight f32 -> bf16: 16 blocks x 64 rows
        size_t base = (size_t)(blk - 192) * 65536;
        for (int i = tid; i < 16384; i += 256) {
            float4 v = *(const float4*)&wp[base + (size_t)i*4];
            *(uint2*)&cpj[base + (size_t)i*4] = make_uint2(pk2bf(v.x,v.y), pk2bf(v.z,v.w));
        }
        return;
    }
    int sel = blk >> 6, d = blk & 63;
    const float* w   = sel==0 ? wq : (sel==1 ? wk : wv);
    const float* mix = sel==0 ? mq : (sel==1 ? mk : mv);
    int c0 = tid * 4;
    float4 wrow[16];
#pragma unroll
    for (int m=0;m<16;++m) wrow[m] = *(const float4*)&w[(size_t)(m*64 + d)*1024 + c0];
#pragma unroll
    for (int h=0;h<16;++h) {
        float ax=0.f, ay=0.f, az=0.f, aw=0.f;
#pragma unroll
        for (int m=0;m<16;++m) {
            float mv_ = mix[h*16 + m];
            ax += mv_*wrow[m].x; ay += mv_*wrow[m].y; az += mv_*wrow[m].z; aw += mv_*wrow[m].w;
        }
        *(uint2*)&whi[(size_t)((sel*16 + h)*64 + d)*1024 + c0] = make_uint2(pk2bf(ax,ay), pk2bf(az,aw));
    }
}

// ---------------- x -> bf16 ----------------
__global__ __launch_bounds__(256) void xcvt_kernel(const float* __restrict__ xf, u16* __restrict__ xb)
{
    int i = blockIdx.x*256 + threadIdx.x;     // i < BTv*Cv/4
    float4 v = ((const float4*)xf)[i];
    ((uint2*)xb)[i] = make_uint2(pk2bf(v.x,v.y), pk2bf(v.z,v.w));
}

// ---------------- bf16 MFMA GEMM (m97-style): Y[M,N] = X[M,K]*W[N,K]^T, f32 out ----------------
// BK=64, global_load_lds width16 with pre-swizzled source; 4 waves 2x2.
template<int BM, int BN>
__global__ __launch_bounds__(256) void gemm_bf16_kernel(
    const u16* __restrict__ X, const u16* __restrict__ W, float* __restrict__ Y,
    int M, int N, int K)
{
    constexpr int MR = BM/32, NR = BN/32;
    constexpr int ACALLS = (BM*8)/256, BCALLS = (BN*8)/256;
    __shared__ __align__(16) u16 As[BM*64];
    __shared__ __align__(16) u16 Bs[BN*64];
    int tid = threadIdx.x;
    int wv = tid >> 6, lane = tid & 63;
    int wr = wv >> 1, wc = wv & 1;
    int c = lane & 15, g = lane >> 4;
    int bm = blockIdx.y * BM, bn = blockIdx.x * BN;
    int r_ = tid >> 3, s_ = tid & 7;

    f32x4 acc[MR][NR];
#pragma unroll
    for (int i=0;i<MR;++i)
#pragma unroll
        for (int j=0;j<NR;++j) acc[i][j] = (f32x4){0.f,0.f,0.f,0.f};

    for (int k0 = 0; k0 < K; k0 += 64) {
#pragma unroll
        for (int i=0;i<ACALLS;++i) {
            int row = i*32 + r_;
            GLOAD16(X + (size_t)(bm+row)*K + k0 + ((s_ ^ (row&7))*8),
                    (u16*)As + i*2048 + wv*512);
        }
#pragma unroll
        for (int i=0;i<BCALLS;++i) {
            int row = i*32 + r_;
            GLOAD16(W + (size_t)(bn+row)*K + k0 + ((s_ ^ (row&7))*8),
                    (u16*)Bs + i*2048 + wv*512);
        }
        __syncthreads();          // drains vmcnt(0): tile landed
#pragma unroll
        for (int kh=0; kh<2; ++kh) {
            short8 a[MR], b[NR];
#pragma unroll
            for (int i=0;i<MR;++i) {
                int row = wr*(BM/2) + i*16 + c;
                a[i] = *(const short8*)&As[row*64 + (((kh*4+g) ^ (c&7))*8)];
            }
#pragma unroll
            for (int j=0;j<NR;++j) {
                int row = wc*(BN/2) + j*16 + c;
                b[j] = *(const short8*)&Bs[row*64 + (((kh*4+g) ^ (c&7))*8)];
            }
#pragma unroll
            for (int i=0;i<MR;++i)
#pragma unroll
                for (int j=0;j<NR;++j)
                    acc[i][j] = __builtin_amdgcn_mfma_f32_16x16x32_bf16(a[i], b[j], acc[i][j], 0,0,0);
        }
        __syncthreads();          // all reads done before next stage overwrites
    }
#pragma unroll
    for (int i=0;i<MR;++i)
#pragma unroll
        for (int j=0;j<NR;++j)
#pragma unroll
            for (int rr=0;rr<4;++rr)
                Y[(size_t)(bm + wr*(BM/2) + i*16 + g*4 + rr)*N + bn + wc*(BN/2) + j*16 + c] = acc[i][j][rr];
}

// ---------------- gates + RoPE + RMS-norm + k time-shift -> bf16 [b,h,t,d] ----------------
__global__ __launch_bounds__(256) void post_kernel(
    const float* __restrict__ x, const float* __restrict__ ve,
    const float* __restrict__ cosT, const float* __restrict__ sinT,
    const float* __restrict__ vegw, const float* __restrict__ atgw,
    float* __restrict__ qkv, float* __restrict__ gateA,
    u16* __restrict__ qbf, u16* __restrict__ kbf)
{
    int bt = blockIdx.x;
    int b = bt >> 11;
    int t = bt & (Tv-1);
    int wave = threadIdx.x >> 6;
    int lane = threadIdx.x & 63;
    int h = blockIdx.y*4 + wave;
    size_t base = (size_t)bt*3072 + h*DHv;
    size_t bh = (size_t)b*Hv + h;

    float gv  = (lane < 32) ? x[(size_t)bt*Cv + lane] * vegw[h*32 + lane] : 0.f;
    float gaP = (lane < 12) ? x[(size_t)bt*Cv + lane] * atgw[h*12 + lane] : 0.f;
#pragma unroll
    for (int off=32; off; off>>=1) {
        gv  += __shfl_xor(gv,  off);
        gaP += __shfl_xor(gaP, off);
    }
    float gateV = 2.f / (1.f + expf(-gv));
    float ga    = 1.f / (1.f + expf(-gaP));
    if (lane == 0) gateA[(size_t)bt*Hv + h] = ga;

    qkv[base + 2048 + lane] += gateV * ve[(size_t)bt*Cv + h*DHv + lane];

    float cs = cosT[t*32 + (lane & 31)];
    float sn = sinT[t*32 + (lane & 31)];

    float qa = qkv[base + lane];
    float qb = __shfl_xor(qa, 32);
    float qr = qa*cs + ((lane < 32) ? qb*sn : -qb*sn);
    float ss = qr*qr;
#pragma unroll
    for (int off=32; off; off>>=1) ss += __shfl_xor(ss, off);
    float qn = qr * rsqrtf(ss*(1.f/64.f) + 1e-6f);
    qbf[(bh*Tv + t)*DHv + lane] = f2bf(qn);

    float ka = qkv[base + 1024 + lane];
    float kb = __shfl_xor(ka, 32);
    float kr = ka*cs + ((lane < 32) ? kb*sn : -kb*sn);
    float s2 = kr*kr;
#pragma unroll
    for (int off=32; off; off>>=1) s2 += __shfl_xor(s2, off);
    float kn = kr * rsqrtf(s2*(1.f/64.f) + 1e-6f);
    if (lane < 32) {
        kbf[(bh*Tv + t)*DHv + lane] = f2bf(kn);
    } else {
        if (t == 0)   kbf[(bh*Tv + 0)*DHv + lane] = f2bf(kn);
        if (t+1 < Tv) kbf[(bh*Tv + t + 1)*DHv + lane] = f2bf(kn);
    }
}

// ---------------- V transpose: f32 qkv v-part -> bf16 [b,h,d,t] ----------------
__global__ __launch_bounds__(256) void vt_kernel(
    const float* __restrict__ qkv, u16* __restrict__ vT)
{
    __shared__ float Ls[64][65];
    int t0 = blockIdx.x * 64;
    int h  = blockIdx.y;
    int b  = blockIdx.z;
    int tid = threadIdx.x;
    for (int i = tid; i < 4096; i += 256) {
        int tt = i >> 6, d = i & 63;
        Ls[tt][d] = qkv[((size_t)(b*Tv + t0 + tt))*3072 + 2048 + h*DHv + d];
    }
    __syncthreads();
    size_t ob = ((size_t)(b*Hv + h))*DHv;
    for (int i = tid; i < 4096; i += 256) {
        int dv = i >> 6, tt = i & 63;
        vT[(ob + dv)*Tv + t0 + tt] = f2bf(Ls[tt][dv]);
    }
}

// ---------------- MFMA flash attention: gload_lds staged, dbuf, 3 blocks/CU ----------------
__global__ __launch_bounds__(256) void attn_mfma_kernel(
    const u16* __restrict__ qbf, const u16* __restrict__ kbf,
    const u16* __restrict__ vT, const float* __restrict__ gateA,
    u16* __restrict__ ybf, const int* __restrict__ wptr)
{
    __shared__ __align__(16) u16 Ks[2][64*64];
    __shared__ __align__(16) u16 Vt[2][64*64];
    __shared__ __align__(16) u16 Pl[4][32][76];   // 52224 B total -> 3 blocks/CU

    int qtile = (int)gridDim.x - 1 - (int)blockIdx.x;   // longest-first
    int h = blockIdx.y, b = blockIdx.z;
    int tid = threadIdx.x, wvi = tid >> 6, lane = tid & 63;
    int c = lane & 15, g = lane >> 4;
    int qbase = qtile*128 + wvi*32;
    int wsz = *wptr;
    bool use_w = !(wsz < 0 || wsz >= Tv-1);

    size_t bh = (size_t)b*Hv + h;
    const u16* qb = qbf + (bh*(size_t)Tv + qbase)*DHv;
    short8 A[2][2];
#pragma unroll
    for (int rb=0; rb<2; ++rb)
#pragma unroll
        for (int kh=0; kh<2; ++kh)
            A[rb][kh] = *(const short8*)(qb + (size_t)(rb*16+c)*DHv + kh*32 + g*8);

    f32x4 zero4 = {0.f,0.f,0.f,0.f};
    f32x4 O[2][4], L[2];
#pragma unroll
    for (int rb=0;rb<2;++rb){ L[rb]=zero4;
#pragma unroll
        for (int dg=0;dg<4;++dg) O[rb][dg]=zero4; }

    short8 ONES;
#pragma unroll
    for (int i=0;i<8;++i) ONES[i] = (short)0x3F80;   // bf16 1.0

    int kt_hi = qtile*2 + 1;
    int kt_lo = 0;
    if (use_w) { int lo = qtile*128 - wsz; if (lo > 0) kt_lo = lo >> 6; }
    const float C1 = 0.18033688f;    // 0.125 * log2(e)
    const float C2 = -11.5415606f;   // -8 * log2(e)

    const u16* gK = kbf + bh*(size_t)Tv*DHv;
    const u16* gV = vT  + bh*(size_t)(DHv*Tv);
    int r_ = tid >> 3, s_ = tid & 7;
    int r0 = r_, r1 = r_ + 32;

    auto stage = [&](int buf, int kt) {   // async: 4 gload_lds per wave, pre-swizzled src
        GLOAD16(gK + (size_t)kt*4096 + r0*64 + ((s_ ^ (r0&7))*8), (u16*)&Ks[buf][0] + wvi*512);
        GLOAD16(gK + (size_t)kt*4096 + r1*64 + ((s_ ^ (r1&7))*8), (u16*)&Ks[buf][0] + 2048 + wvi*512);
        GLOAD16(gV + (size_t)r0*Tv + kt*64 + ((s_ ^ (r0&7))*8),   (u16*)&Vt[buf][0] + wvi*512);
        GLOAD16(gV + (size_t)r1*Tv + kt*64 + ((s_ ^ (r1&7))*8),   (u16*)&Vt[buf][0] + 2048 + wvi*512);
    };

    auto compute = [&](int kt, int cur) {
        short8 Bk[4][2];
#pragma unroll
        for (int kg=0;kg<4;++kg)
#pragma unroll
            for (int kh=0;kh<2;++kh)
                Bk[kg][kh] = *(const short8*)&Ks[cur][(kg*16+c)*64 + (((kh*4+g) ^ (c&7))*8)];
        f32x4 S[2][4];
#pragma unroll
        for (int rb=0;rb<2;++rb)
#pragma unroll
            for (int kg=0;kg<4;++kg) {
                S[rb][kg] = __builtin_amdgcn_mfma_f32_16x16x32_bf16(A[rb][0], Bk[kg][0], zero4, 0,0,0);
                S[rb][kg] = __builtin_amdgcn_mfma_f32_16x16x32_bf16(A[rb][1], Bk[kg][1], S[rb][kg], 0,0,0);
            }
        bool needmask = (kt*64 + 63 > qbase) || (use_w && (kt*64 < qbase + 31 - wsz));
#pragma unroll
        for (int rb=0;rb<2;++rb)
#pragma unroll
            for (int kg=0;kg<4;++kg)
#pragma unroll
                for (int r=0;r<4;++r) {
                    float t = fmaf(S[rb][kg][r], C1, C2);   // exp2 domain
                    if (needmask) {
                        int key = kt*64 + kg*16 + c;
                        int qg  = qbase + rb*16 + g*4 + r;
                        bool ok = (key <= qg) && (!use_w || (qg - key <= wsz));
                        t = ok ? t : -1e30f;
                    }
                    Pl[wvi][rb*16 + g*4 + r][kg*16 + c] = f2bf(fexp2(t));
                }
        asm volatile("s_waitcnt lgkmcnt(0)" ::: "memory");
        __builtin_amdgcn_sched_barrier(0);
        short8 Vf[4][2];
#pragma unroll
        for (int dg=0;dg<4;++dg)
#pragma unroll
            for (int kh=0;kh<2;++kh)
                Vf[dg][kh] = *(const short8*)&Vt[cur][(dg*16+c)*64 + (((kh*4+g) ^ (c&7))*8)];
#pragma unroll
        for (int rb=0;rb<2;++rb) {
            short8 PA0 = *(const short8*)&Pl[wvi][rb*16+c][g*8];
            short8 PA1 = *(const short8*)&Pl[wvi][rb*16+c][32 + g*8];
            L[rb] = __builtin_amdgcn_mfma_f32_16x16x32_bf16(PA0, ONES, L[rb], 0,0,0);
            L[rb] = __builtin_amdgcn_mfma_f32_16x16x32_bf16(PA1, ONES, L[rb], 0,0,0);
#pragma unroll
            for (int dg=0;dg<4;++dg) {
                O[rb][dg] = __builtin_amdgcn_mfma_f32_16x16x32_bf16(PA0, Vf[dg][0], O[rb][dg], 0,0,0);
                O[rb][dg] = __builtin_amdgcn_mfma_f32_16x16x32_bf16(PA1, Vf[dg][1], O[rb][dg], 0,0,0);
            }
        }
    };

    stage(0, kt_lo);
    __syncthreads();
    int cur = 0;
    for (int kt = kt_lo; kt <= kt_hi; ++kt) {
        if (kt < kt_hi) stage(cur^1, kt+1);   // loads fly across compute
        compute(kt, cur);
        __syncthreads();                      // drains vmcnt(0) + lgkm + barrier
        cur ^= 1;
    }

    float gar[2][4], linv[2][4];
#pragma unroll
    for (int rb=0;rb<2;++rb)
#pragma unroll
        for (int r=0;r<4;++r) {
            gar[rb][r]  = gateA[(size_t)(b*Tv + qbase + rb*16 + g*4 + r)*Hv + h];
            linv[rb][r] = 1.f / L[rb][r];
        }
#pragma unroll
    for (int rb=0;rb<2;++rb)
#pragma unroll
        for (int dg=0;dg<4;++dg)
#pragma unroll
            for (int r=0;r<4;++r)
                ybf[((size_t)(b*Tv + qbase + rb*16 + g*4 + r))*Cv + h*DHv + dg*16 + c] =
                    f2bf(O[rb][dg][r] * linv[rb][r] * gar[rb][r]);
}

extern "C" void kernel_launch(void* const* d_in, const int* in_sizes, int n_in,
                              void* d_out, int out_size, void* d_ws, size_t ws_size,
                              hipStream_t stream) {
    const float* x    = (const float*)d_in[0];
    const float* ve   = (const float*)d_in[1];
    const float* cosT = (const float*)d_in[2];
    const float* sinT = (const float*)d_in[3];
    const float* cqw  = (const float*)d_in[4];
    const float* ckw  = (const float*)d_in[5];
    const float* cvw  = (const float*)d_in[6];
    const float* cpw  = (const float*)d_in[7];
    const float* vegw = (const float*)d_in[8];
    const float* atgw = (const float*)d_in[9];
    const float* qmix = (const float*)d_in[10];
    const float* kmix = (const float*)d_in[11];
    const float* vmix = (const float*)d_in[12];
    const int*   wsz  = (const int*)d_in[13];
    float* out = (float*)d_out;

    const size_t M1 = 1u << 20;
    float* p0 = (float*)d_ws;
    float* qkv = p0;
    u16*   cpj = (u16*)(p0 + 12*M1);
    float* ga  = p0 + 12*M1 + M1/2;
    u16*   qbf = (u16*)(p0 + 13*M1);
    u16*   kbf = (u16*)(p0 + 15*M1);
    u16*   vT  = (u16*)(p0 + 17*M1);
    u16*   whi = (u16*)(p0 + 13*M1);
    u16*   xbf = (u16*)(p0 + 15*M1);
    u16*   ybf = (u16*)p0;

    fuse_w_kernel<<<208, 256, 0, stream>>>(cqw, ckw, cvw, cpw, qmix, kmix, vmix, whi, cpj);
    xcvt_kernel<<<(BTv*Cv/4)/256, 256, 0, stream>>>(x, xbf);

    gemm_bf16_kernel<128,128><<<dim3(3072/128, BTv/128), 256, 0, stream>>>(
        xbf, whi, qkv, BTv, 3072, Cv);

    post_kernel<<<dim3(BTv, Hv/4), 256, 0, stream>>>(x, ve, cosT, sinT, vegw, atgw,
                                                     qkv, ga, qbf, kbf);

    vt_kernel<<<dim3(Tv/64, Hv, Bv), 256, 0, stream>>>(qkv, vT);

    attn_mfma_kernel<<<dim3(Tv/128, Hv, Bv), 256, 0, stream>>>(qbf, kbf, vT, ga, ybf, wsz);

    gemm_bf16_kernel<128,64><<<dim3(Cv/64, BTv/128), 256, 0, stream>>>(
        ybf, cpj, out, BTv, Cv, Cv);
}